// Round 4
// baseline (55.020 us; speedup 1.0000x reference)
//
#include <hip/hip_runtime.h>
#include <math.h>

// Problem constants (from reference setup_inputs)
#define B_ 32
#define S_ 8192
#define H_ 256
#define CHUNK_ 256                      // rows per block (was 512)
#define WAVES_PB 4                      // 256 threads
#define WROWS (CHUNK_ / WAVES_PB)       // 64 rows per wave
#define TILE_ 8                         // rows per register tile (was 16)
#define NCHUNK (S_ / CHUNK_)            // 32 blocks per batch
#define NPART (B_ * NCHUNK * WAVES_PB)  // 4096 per-wave partials
#define PPB (NCHUNK * WAVES_PB)         // 128 partials per batch

// K1: flash-style single pass over encoder_states.
// Grid 1024 blocks (4/CU), 16 waves/CU — tests parallelism-limit hypothesis.
__global__ __launch_bounds__(256) void
k1_flash(const float* __restrict__ dec, const float* __restrict__ enc,
         float* __restrict__ scores_out, float* __restrict__ pm,
         float* __restrict__ pl, float* __restrict__ pc) {
    const int lane  = threadIdx.x & 63;
    const int wave  = threadIdx.x >> 6;
    const int batch = blockIdx.x >> 5;        // / NCHUNK
    const int chunk = blockIdx.x & (NCHUNK - 1);
    const int rowBase = chunk * CHUNK_ + wave * WROWS;

    const float4 d = *(const float4*)(dec + batch * H_ + lane * 4);
    const float* ebase = enc + (size_t)batch * S_ * H_;

    float  m = -INFINITY, l = 0.f;
    float4 c = make_float4(0.f, 0.f, 0.f, 0.f);

    for (int t = 0; t < WROWS / TILE_; ++t) {
        const int r0 = rowBase + t * TILE_;
        float4 v[TILE_];
        float  sc[TILE_];
#pragma unroll
        for (int r = 0; r < TILE_; ++r) {
            v[r] = *(const float4*)(ebase + (size_t)(r0 + r) * H_ + lane * 4);
            float sp = v[r].x * d.x + v[r].y * d.y + v[r].z * d.z + v[r].w * d.w;
#pragma unroll
            for (int off = 32; off; off >>= 1) sp += __shfl_xor(sp, off);
            sc[r] = sp;                      // all 64 lanes hold the row sum
        }
        float tmax = sc[0];
#pragma unroll
        for (int r = 1; r < TILE_; ++r) tmax = fmaxf(tmax, sc[r]);
        const float mnew = fmaxf(m, tmax);
        const float f = __expf(m - mnew);    // first tile: exp(-inf)=0
        c.x *= f; c.y *= f; c.z *= f; c.w *= f;
        l *= f;
        m = mnew;
#pragma unroll
        for (int r = 0; r < TILE_; ++r) {
            const float p = __expf(sc[r] - m);
            l += p;
            c.x += p * v[r].x;
            c.y += p * v[r].y;
            c.z += p * v[r].z;
            c.w += p * v[r].w;
        }
        if (lane == 0) {                     // raw scores, 2x float4
            float* so = scores_out + batch * S_ + r0;
            *(float4*)(so + 0) = make_float4(sc[0], sc[1], sc[2], sc[3]);
            *(float4*)(so + 4) = make_float4(sc[4], sc[5], sc[6], sc[7]);
        }
    }

    // pid = batch*128 + chunk*4 + wave (contiguous per batch)
    const int pid = blockIdx.x * WAVES_PB + wave;
    *(float4*)(pc + (size_t)pid * H_ + lane * 4) = c;
    if (lane == 0) { pm[pid] = m; pl[pid] = l; }
}

// K23: fused finish. Blocks 0..255: prob fixup. Blocks 256..287: context.
// (M, L) derived from the 128 per-batch partials: 2 per lane + butterfly.
__global__ __launch_bounds__(256) void
k23_finish(const float* __restrict__ pm, const float* __restrict__ pl,
           const float* __restrict__ pc, float* __restrict__ probs,
           float* __restrict__ ctx_out) {
    const int lane = threadIdx.x & 63;
    const int b = (blockIdx.x < 256) ? (blockIdx.x >> 3) : (blockIdx.x - 256);

    const float pm0 = pm[b * PPB + lane];
    const float pm1 = pm[b * PPB + 64 + lane];
    const float pl0 = pl[b * PPB + lane];
    const float pl1 = pl[b * PPB + 64 + lane];
    float M = fmaxf(pm0, pm1);
#pragma unroll
    for (int off = 32; off; off >>= 1) M = fmaxf(M, __shfl_xor(M, off));
    const float w0 = __expf(pm0 - M);
    const float w1 = __expf(pm1 - M);
    float L = w0 * pl0 + w1 * pl1;
#pragma unroll
    for (int off = 32; off; off >>= 1) L += __shfl_xor(L, off);
    const float R = 1.f / L;

    if (blockIdx.x < 256) {
        // ---- prob fixup: 8 blocks per batch, 1024 floats per block ----
        float* p = probs + b * S_ + (blockIdx.x & 7) * 1024 + threadIdx.x * 4;
        float4 v = *(const float4*)p;
        v.x = __expf(v.x - M) * R;
        v.y = __expf(v.y - M) * R;
        v.z = __expf(v.z - M) * R;
        v.w = __expf(v.w - M) * R;
        *(float4*)p = v;
    } else {
        // ---- context combine: one block per batch, thread h owns one H ----
        const int h = threadIdx.x;
        float acc = 0.f;
        const float* pcb = pc + (size_t)b * PPB * H_ + h;
#pragma unroll 8
        for (int i = 0; i < 64; ++i)
            acc += __shfl(w0, i) * pcb[(size_t)i * H_];
#pragma unroll 8
        for (int i = 0; i < 64; ++i)
            acc += __shfl(w1, i) * pcb[(size_t)(64 + i) * H_];
        ctx_out[b * H_ + h] = acc * R;
    }
}

extern "C" void kernel_launch(void* const* d_in, const int* in_sizes, int n_in,
                              void* d_out, int out_size, void* d_ws, size_t ws_size,
                              hipStream_t stream) {
    const float* dec = (const float*)d_in[0];
    const float* enc = (const float*)d_in[1];
    float* out    = (float*)d_out;
    float* probs  = out;              // [B_*S_] doubles as raw-score scratch
    float* ctx    = out + B_ * S_;    // [B_*H_]

    float* pm = (float*)d_ws;                  // [NPART]
    float* pl = pm + NPART;                    // [NPART]
    float* pc = pl + NPART;                    // [NPART*H_]

    k1_flash<<<B_ * NCHUNK, 256, 0, stream>>>(dec, enc, probs, pm, pl, pc);
    k23_finish<<<256 + B_, 256, 0, stream>>>(pm, pl, pc, probs, ctx);
}